// Round 3
// baseline (92.226 us; speedup 1.0000x reference)
//
#include <hip/hip_runtime.h>
#include <hip/hip_bf16.h>

// N=8192, D=512. Algebraic reduction (verified R1/R2, absmax 3.8e-6):
//   softmax row-sums are exactly 1 => attn.mean(heads).mean(keys) == 1/N
//   b_q = sigmoid(r)/(sum sigmoid(r) + N*1e-8);  Wq/Wk provably unused.
//   attended = (patch * b_q[:,None]) @ Wout^T
// Out layout: attended (N*D fp32) then b_q (N fp32).
//
// R3: SINGLE fused kernel. Each block redundantly computes the global
// sigmoid-sum (identical reduction order => bitwise-consistent inv, no
// cross-block sync), stages its 64-row A strip once through LDS (fused
// fp32->bf16), streams B frags straight from L2-resident fp32 Wout with
// inline cvt (no pre-convert kernel, no d_ws), scales by b_q in epilogue.
// One barrier total. dur_us is dominated by fixed harness poison (~44us
// ws fill seen in R2 profile); kernel-side floor = ~36MB HBM = 5.7us.

#define NPTS 8192
#define DDIM 512
#define BM   64
#define LDK  (DDIM + 8)   // bf16 row stride 1040B: 16B-group rotation, balanced banks

typedef __attribute__((ext_vector_type(8))) short bf16x8;
typedef __attribute__((ext_vector_type(4))) float f32x4;
typedef __attribute__((ext_vector_type(4))) unsigned short us4;
typedef __attribute__((ext_vector_type(8))) unsigned short us8;

static __device__ __forceinline__ unsigned short f2bf(float f) {
    unsigned int u = __float_as_uint(f);
    u += 0x7fffu + ((u >> 16) & 1u);     // RNE fp32->bf16
    return (unsigned short)(u >> 16);
}

static __device__ __forceinline__ float sigmoidf(float x) {
    return 1.0f / (1.0f + expf(-x));
}

// grid(128,2) x 512 thr. Block = 64 rows x 256 cols; wave w owns cols
// [half*256 + w*32, +32) as a 4x2 grid of 16x16 MFMA tiles over all 64 rows.
__global__ __launch_bounds__(512) void fused_kernel(const float* __restrict__ A,
                                                    const float* __restrict__ r,
                                                    const float* __restrict__ W,
                                                    float* __restrict__ out) {
    __shared__ unsigned short As[BM][LDK];
    __shared__ float wsum[8];

    const int rs   = blockIdx.x;   // 0..127 row strip; blocks rs and rs+128
    const int half = blockIdx.y;   // share the strip and land on the same XCD
    const int tid  = threadIdx.x;
    const int wave = tid >> 6;
    const int lane = tid & 63;
    const int quad = lane >> 4, l16 = lane & 15;

    float* bq_out = out + (size_t)NPTS * DDIM;

    // ---- phase 0: redundant global sigmoid-sum (same order in every block) ----
    float local = 0.0f;
#pragma unroll
    for (int k = 0; k < 16; ++k)
        local += sigmoidf(r[tid + 512 * k]);
#pragma unroll
    for (int off = 32; off >= 1; off >>= 1)
        local += __shfl_down(local, off, 64);
    if (lane == 0) wsum[wave] = local;

    // ---- phase 0b: stage A strip (64x512 fp32 -> bf16 LDS), coalesced ----
    const float* Ab = A + (size_t)rs * BM * DDIM;
#pragma unroll
    for (int i = 0; i < 16; ++i) {
        const int f = tid * 4 + i * 2048;          // 0..32767
        float4 v = *(const float4*)(Ab + f);
        us4 o = { f2bf(v.x), f2bf(v.y), f2bf(v.z), f2bf(v.w) };
        *(us4*)&As[f >> 9][f & 511] = o;
    }
    __syncthreads();   // the only barrier

    float stot = 0.0f;
#pragma unroll
    for (int i = 0; i < 8; ++i) stot += wsum[i];   // redundant per-thread, no 2nd barrier
    const float inv = 1.0f / (stot + (float)NPTS * 1e-8f);

    // ---- K-loop: B frags from L2-resident fp32 W, inline cvt, zero barriers ----
    const int c0 = half * 256 + wave * 32;
    // B operand (16x16x32): lane holds W[n = c0+j*16+l16][k = kc*32+quad*8 ..+8]
    const float* wb0 = W + (size_t)(c0 + l16) * DDIM + quad * 8;
    const float* wb1 = wb0 + 16 * DDIM;

    f32x4 acc[4][2] = {};

    float4 c0a = *(const float4*)(wb0);
    float4 c0b = *(const float4*)(wb0 + 4);
    float4 c1a = *(const float4*)(wb1);
    float4 c1b = *(const float4*)(wb1 + 4);

#pragma unroll
    for (int kc = 0; kc < 16; ++kc) {
        float4 n0a, n0b, n1a, n1b;
        if (kc < 15) {
            const float* p0 = wb0 + (kc + 1) * 32;
            const float* p1 = wb1 + (kc + 1) * 32;
            n0a = *(const float4*)(p0);
            n0b = *(const float4*)(p0 + 4);
            n1a = *(const float4*)(p1);
            n1b = *(const float4*)(p1 + 4);
        }
        us8 b0 = { f2bf(c0a.x), f2bf(c0a.y), f2bf(c0a.z), f2bf(c0a.w),
                   f2bf(c0b.x), f2bf(c0b.y), f2bf(c0b.z), f2bf(c0b.w) };
        us8 b1 = { f2bf(c1a.x), f2bf(c1a.y), f2bf(c1a.z), f2bf(c1a.w),
                   f2bf(c1b.x), f2bf(c1b.y), f2bf(c1b.z), f2bf(c1b.w) };
        const int kb = kc * 32 + quad * 8;
        bf16x8 a0 = *(const bf16x8*)&As[l16][kb];
        bf16x8 a1 = *(const bf16x8*)&As[16 + l16][kb];
        bf16x8 a2 = *(const bf16x8*)&As[32 + l16][kb];
        bf16x8 a3 = *(const bf16x8*)&As[48 + l16][kb];
        acc[0][0] = __builtin_amdgcn_mfma_f32_16x16x32_bf16(a0, (bf16x8)b0, acc[0][0], 0, 0, 0);
        acc[1][0] = __builtin_amdgcn_mfma_f32_16x16x32_bf16(a1, (bf16x8)b0, acc[1][0], 0, 0, 0);
        acc[2][0] = __builtin_amdgcn_mfma_f32_16x16x32_bf16(a2, (bf16x8)b0, acc[2][0], 0, 0, 0);
        acc[3][0] = __builtin_amdgcn_mfma_f32_16x16x32_bf16(a3, (bf16x8)b0, acc[3][0], 0, 0, 0);
        acc[0][1] = __builtin_amdgcn_mfma_f32_16x16x32_bf16(a0, (bf16x8)b1, acc[0][1], 0, 0, 0);
        acc[1][1] = __builtin_amdgcn_mfma_f32_16x16x32_bf16(a1, (bf16x8)b1, acc[1][1], 0, 0, 0);
        acc[2][1] = __builtin_amdgcn_mfma_f32_16x16x32_bf16(a2, (bf16x8)b1, acc[2][1], 0, 0, 0);
        acc[3][1] = __builtin_amdgcn_mfma_f32_16x16x32_bf16(a3, (bf16x8)b1, acc[3][1], 0, 0, 0);
        c0a = n0a; c0b = n0b; c1a = n1a; c1b = n1b;
    }

    // ---- epilogue: C/D layout col=l16, row=quad*4+reg [m89/m91] ----
    // scale recomputed per row (broadcast r load + expf beats an extra barrier)
#pragma unroll
    for (int i = 0; i < 4; ++i) {
        const int rbase = rs * BM + i * 16 + quad * 4;
#pragma unroll
        for (int rg = 0; rg < 4; ++rg) {
            const int grow = rbase + rg;
            const float scale = sigmoidf(r[grow]) * inv;
            out[(size_t)grow * DDIM + c0 + l16]      = acc[i][0][rg] * scale;
            out[(size_t)grow * DDIM + c0 + 16 + l16] = acc[i][1][rg] * scale;
        }
    }

    // ---- b_q tail: each strip written once (by its half==0 block) ----
    if (half == 0 && tid < BM) {
        const int n = rs * BM + tid;
        bq_out[n] = sigmoidf(r[n]) * inv;
    }
}

extern "C" void kernel_launch(void* const* d_in, const int* in_sizes, int n_in,
                              void* d_out, int out_size, void* d_ws, size_t ws_size,
                              hipStream_t stream) {
    const float* patch = (const float*)d_in[0];   // (8192, 512)
    const float* resid = (const float*)d_in[1];   // (8192,)
    // d_in[2]=Wq, d_in[3]=Wk unused (softmax row-sums are exactly 1)
    const float* wout  = (const float*)d_in[4];   // (512, 512)
    float* out = (float*)d_out;

    fused_kernel<<<dim3(128, 2), 512, 0, stream>>>(patch, resid, wout, out);
}

// Round 4
// 87.426 us; speedup vs baseline: 1.0549x; 1.0549x over previous
//
#include <hip/hip_runtime.h>
#include <hip/hip_bf16.h>

// N=8192, D=512. Algebraic reduction (verified R1-R3, absmax 3.8e-6):
//   softmax row-sums are exactly 1 => attn.mean(heads).mean(keys) == 1/N
//   b_q = sigmoid(r)/(sum sigmoid(r) + N*1e-8);  Wq/Wk provably unused.
//   attended = (patch * b_q[:,None]) @ Wout^T
// Out layout: attended (N*D fp32) then b_q (N fp32).
//
// R4 = best of R2 + R3:
//   k1: pure Wout fp32->bf16 into d_ws (128 parallel blocks, ~1.2us,
//       no serial b_q block gating the GEMM launch).
//   k2: GEMM with bf16 B straight from L2 (half the B traffic of R3's
//       fp32 path, zero cvt on the K-loop critical path), A staged once
//       through LDS with fused cvt, redundant per-block sigmoid-sum
//       (identical reduction order => bitwise-consistent inv, no
//       cross-block sync), b_q applied in epilogue. One barrier total.
// Measured budget: harness re-poison floor ~80us (268MB ws fill = 44us
// @75% HBM peak + out poison + restores + gaps); kernel floor 5.7us.

#define NPTS 8192
#define DDIM 512
#define BM   64
#define LDK  (DDIM + 8)   // bf16 row stride 1040B = 65*16B (odd) -> conflict-free b128

typedef __attribute__((ext_vector_type(8))) short bf16x8;
typedef __attribute__((ext_vector_type(4))) float f32x4;
typedef __attribute__((ext_vector_type(4))) unsigned short us4;
typedef __attribute__((ext_vector_type(8))) unsigned short us8;

static __device__ __forceinline__ unsigned short f2bf(float f) {
    unsigned int u = __float_as_uint(f);
    u += 0x7fffu + ((u >> 16) & 1u);     // RNE fp32->bf16
    return (unsigned short)(u >> 16);
}

static __device__ __forceinline__ float sigmoidf(float x) {
    return 1.0f / (1.0f + expf(-x));
}

// ---------------------------------------------------------------------------
// Kernel 1: Wout (512x512 fp32) -> bf16 in ws. Fully parallel, ~1.2us.
// ---------------------------------------------------------------------------
__global__ __launch_bounds__(256) void wcvt_kernel(const float* __restrict__ wout,
                                                   unsigned short* __restrict__ wbf) {
    const int f = blockIdx.x * 2048 + threadIdx.x * 8;
    float4 v0 = *(const float4*)(wout + f);
    float4 v1 = *(const float4*)(wout + f + 4);
    us8 o = { f2bf(v0.x), f2bf(v0.y), f2bf(v0.z), f2bf(v0.w),
              f2bf(v1.x), f2bf(v1.y), f2bf(v1.z), f2bf(v1.w) };
    *(us8*)(wbf + f) = o;
}

// ---------------------------------------------------------------------------
// Kernel 2: out[n,o] = b_q[n] * dot(patch[n,:], Wout[o,:])
// grid(128,2) x 512 thr. Block = 64 rows x 256 cols; wave w owns cols
// [half*256 + w*32, +32) as 4x2 16x16 MFMA tiles over all 64 rows.
// ---------------------------------------------------------------------------
__global__ __launch_bounds__(512) void gemm_kernel(const float* __restrict__ A,
                                                   const float* __restrict__ r,
                                                   const unsigned short* __restrict__ wbf,
                                                   float* __restrict__ out) {
    __shared__ unsigned short As[BM][LDK];
    __shared__ float wsum[8];

    const int rs   = blockIdx.x;   // 0..127 row strip; blocks rs and rs+128
    const int half = blockIdx.y;   // share the strip -> same XCD (128 % 8 == 0)
    const int tid  = threadIdx.x;
    const int wave = tid >> 6;
    const int lane = tid & 63;
    const int quad = lane >> 4, l16 = lane & 15;

    float* bq_out = out + (size_t)NPTS * DDIM;

    // ---- phase 0: redundant global sigmoid-sum (same order in every block) ----
    float local = 0.0f;
#pragma unroll
    for (int k = 0; k < 16; ++k)
        local += sigmoidf(r[tid + 512 * k]);
#pragma unroll
    for (int off = 32; off >= 1; off >>= 1)
        local += __shfl_down(local, off, 64);
    if (lane == 0) wsum[wave] = local;

    // ---- phase 0b: stage A strip (64x512 fp32 -> bf16 LDS), coalesced ----
    const float* Ab = A + (size_t)rs * BM * DDIM;
#pragma unroll
    for (int i = 0; i < 16; ++i) {
        const int f = tid * 4 + i * 2048;          // 0..32767
        float4 v = *(const float4*)(Ab + f);
        us4 o = { f2bf(v.x), f2bf(v.y), f2bf(v.z), f2bf(v.w) };
        *(us4*)&As[f >> 9][f & 511] = o;
    }
    __syncthreads();   // the only barrier

    float stot = 0.0f;
#pragma unroll
    for (int i = 0; i < 8; ++i) stot += wsum[i];   // redundant per-thread
    const float inv = 1.0f / (stot + (float)NPTS * 1e-8f);

    // ---- K-loop: bf16 B frags from L2 (512KB total), prefetched, no barriers ----
    const int c0 = half * 256 + wave * 32;
    // B operand (16x16x32): lane holds W[n = c0+j*16+l16][k = kc*32+quad*8 ..+8]
    const unsigned short* wb0 = wbf + (size_t)(c0 + l16) * DDIM + quad * 8;
    const unsigned short* wb1 = wb0 + 16 * DDIM;

    f32x4 acc[4][2] = {};

    bf16x8 bc0 = *(const bf16x8*)(wb0);
    bf16x8 bc1 = *(const bf16x8*)(wb1);

#pragma unroll
    for (int kc = 0; kc < 16; ++kc) {
        bf16x8 bn0, bn1;
        if (kc < 15) {
            bn0 = *(const bf16x8*)(wb0 + (kc + 1) * 32);
            bn1 = *(const bf16x8*)(wb1 + (kc + 1) * 32);
        }
        const int kb = kc * 32 + quad * 8;
        bf16x8 a0 = *(const bf16x8*)&As[l16][kb];
        bf16x8 a1 = *(const bf16x8*)&As[16 + l16][kb];
        bf16x8 a2 = *(const bf16x8*)&As[32 + l16][kb];
        bf16x8 a3 = *(const bf16x8*)&As[48 + l16][kb];
        acc[0][0] = __builtin_amdgcn_mfma_f32_16x16x32_bf16(a0, bc0, acc[0][0], 0, 0, 0);
        acc[1][0] = __builtin_amdgcn_mfma_f32_16x16x32_bf16(a1, bc0, acc[1][0], 0, 0, 0);
        acc[2][0] = __builtin_amdgcn_mfma_f32_16x16x32_bf16(a2, bc0, acc[2][0], 0, 0, 0);
        acc[3][0] = __builtin_amdgcn_mfma_f32_16x16x32_bf16(a3, bc0, acc[3][0], 0, 0, 0);
        acc[0][1] = __builtin_amdgcn_mfma_f32_16x16x32_bf16(a0, bc1, acc[0][1], 0, 0, 0);
        acc[1][1] = __builtin_amdgcn_mfma_f32_16x16x32_bf16(a1, bc1, acc[1][1], 0, 0, 0);
        acc[2][1] = __builtin_amdgcn_mfma_f32_16x16x32_bf16(a2, bc1, acc[2][1], 0, 0, 0);
        acc[3][1] = __builtin_amdgcn_mfma_f32_16x16x32_bf16(a3, bc1, acc[3][1], 0, 0, 0);
        bc0 = bn0;
        bc1 = bn1;
    }

    // ---- epilogue: C/D layout col=l16, row=quad*4+reg [m89/m91] ----
    // scale recomputed per row (broadcast r load + expf beats an extra barrier)
#pragma unroll
    for (int i = 0; i < 4; ++i) {
        const int rbase = rs * BM + i * 16 + quad * 4;
#pragma unroll
        for (int rg = 0; rg < 4; ++rg) {
            const int grow = rbase + rg;
            const float scale = sigmoidf(r[grow]) * inv;
            out[(size_t)grow * DDIM + c0 + l16]      = acc[i][0][rg] * scale;
            out[(size_t)grow * DDIM + c0 + 16 + l16] = acc[i][1][rg] * scale;
        }
    }

    // ---- b_q tail: each strip written once (by its half==0 block) ----
    if (half == 0 && tid < BM) {
        const int n = rs * BM + tid;
        bq_out[n] = sigmoidf(r[n]) * inv;
    }
}

extern "C" void kernel_launch(void* const* d_in, const int* in_sizes, int n_in,
                              void* d_out, int out_size, void* d_ws, size_t ws_size,
                              hipStream_t stream) {
    const float* patch = (const float*)d_in[0];   // (8192, 512)
    const float* resid = (const float*)d_in[1];   // (8192,)
    // d_in[2]=Wq, d_in[3]=Wk unused (softmax row-sums are exactly 1)
    const float* wout  = (const float*)d_in[4];   // (512, 512)
    float* out = (float*)d_out;
    unsigned short* wbf = (unsigned short*)d_ws;  // 512KB bf16 W

    wcvt_kernel<<<128, 256, 0, stream>>>(wout, wbf);
    gemm_kernel<<<dim3(128, 2), 512, 0, stream>>>(patch, resid, wbf, out);
}